// Round 8
// baseline (65.538 us; speedup 1.0000x reference)
//
#include <hip/hip_runtime.h>
#include <hip/hip_bf16.h>
#include <math.h>

typedef __bf16 bf16;
typedef __attribute__((ext_vector_type(4))) float f32x4;
typedef __attribute__((ext_vector_type(8))) bf16 bf16x8;

#define M_TOT 16384
#define K_TOT 1024
#define D_EMB 512
#define NT 32          // K tiles of 32

// ============================================================
// Pass 0 (tiny): W (both heads) f32 -> bf16 "LDS image" in ws.
// Image per (bn, kt): 8 KB block, flat elem f = row*32 + slot*8 + j
// holding W[bn*128+row][kt*32 + (slot ^ ((row>>1)&3))*8 + j].
// GEMM stages it with linear global_load_lds; frag reads apply the
// same XOR -> bank-conflict-free without any ds_write for B.
// ============================================================
__global__ __launch_bounds__(256) void cvt_w_img(
    const float* __restrict__ W_mu, const float* __restrict__ W_logvar,
    bf16* __restrict__ img)
{
    // one thread per 8-elem chunk: 8 bn * 32 kt * 128 row * 4 slot = 131072
    int c = blockIdx.x * blockDim.x + threadIdx.x;
    const int slot = c & 3;
    const int row  = (c >> 2) & 127;
    const int kt   = (c >> 9) & 31;
    const int bn   = c >> 14;
    const int e    = bn * 128 + row;
    const int k0   = kt * 32 + (slot ^ ((row >> 1) & 3)) * 8;
    const float* src = (e < D_EMB) ? (W_mu + (size_t)e * K_TOT + k0)
                                   : (W_logvar + (size_t)(e - D_EMB) * K_TOT + k0);
    f32x4 a = *(const f32x4*)(src);
    f32x4 b = *(const f32x4*)(src + 4);
    bf16x8 o;
    o[0] = (bf16)a[0]; o[1] = (bf16)a[1]; o[2] = (bf16)a[2]; o[3] = (bf16)a[3];
    o[4] = (bf16)b[0]; o[5] = (bf16)b[1]; o[6] = (bf16)b[2]; o[7] = (bf16)b[3];
    *(bf16x8*)(img + (size_t)c * 8) = o;
}

// ============================================================
// Main GEMM: 128x128 tile, BK=32, 4 waves (2x2, 64x64 per wave),
// grid 1024 (bm 128 x bn 8), 32 KB LDS, 3 blocks/CU for cross-block
// overlap of LDS/staging phases with MFMA phases.
//   A: x f32 -> regs (2 tiles ahead, counted vmcnt) -> cvt -> swizzled
//      ds_write (1 tile ahead).  B: pre-swizzled bf16 image in ws ->
//      global_load_lds (1 tile ahead; PER-LANE source = base + lane*8
//      elems, linear dest -- r7 bug was a wave-uniform source).
// Ledger (body t, p=t&1; outstanding FIFO after barrier(t-1)=[A(t+1):4]):
//   s0 [t+1<NT] issue gloadB_lds(t+1)->B[p^1] (2)   [A:4,B:2]
//   s1 [t+1<NT] vmcnt(2) drains A(t+1); cvt; 2 ds_write -> A[p^1]
//   s2 [t+2<NT] issue gloadA(t+2) (4)               [B:2,A':4]
//   s3 ds_read 8 frags (tile t, bufs p)
//   s4 vmcnt(4) drains B(t+1)  (tails: vmcnt(0))
//   s5 lgkm(0); barrier
//   s6 setprio(1); 16 MFMA; setprio(0)
// WAR: buf p^1 last read at body t-1 s3; those ds_reads retired before
// barrier(t-1) (per-wave lgkm(0)); body-t writes issued after it.
// Visibility: A ds_writes drain via s5 lgkm(0)+barrier; B stage via
// s4 counted vmcnt + barrier.
// ============================================================
__global__ __launch_bounds__(256, 3) void gpe_gemm(
    const float* __restrict__ x,
    const bf16* __restrict__ wimg,
    const float* __restrict__ b_mu,
    const float* __restrict__ b_logvar,
    float* __restrict__ out)         // [2][16384][512]
{
    __shared__ __align__(16) bf16 lds[4 * 4096];   // A0,A1,B0,B1 (8KB each)

    const int tid  = threadIdx.x;
    const int lane = tid & 63;
    const int wid  = tid >> 6;        // 0..3
    const int wrm  = wid >> 1;        // 0..1 wave row
    const int wcn  = wid & 1;         // 0..1 wave col

    // T1: bijective XCD swizzle (grid 1024 = 8 XCD x 128); bn inner so the
    // 8 blocks sharing an x-panel (512 KB) sit on one XCD's L2.
    const int bid = blockIdx.x;
    const int swz = (bid & 7) * 128 + (bid >> 3);
    const int bn  = swz & 7;          // 0..7
    const int bm  = swz >> 3;         // 0..127

    const float* __restrict__ Ap  = x + (size_t)(bm * 128) * K_TOT;
    const bf16*  __restrict__ Bip = wimg + (size_t)bn * (32 * 4096);

    // ---- A staging geometry: thread owns 16 f32 of a row ----
    const int r_l  = tid >> 1;                        // 0..127
    const int half = tid & 1;
    const float* __restrict__ Asrc = Ap + (size_t)r_l * K_TOT + half * 16;
    const int wxor  = (r_l >> 1) & 3;
    const int woff0 = r_l * 32 + ((half * 2 + 0) ^ wxor) * 8;   // elems
    const int woff1 = r_l * 32 + ((half * 2 + 1) ^ wxor) * 8;

    // ---- frag read geometry ----
    const int fr  = lane & 15;
    const int g16 = lane >> 4;                        // k-chunk 0..3
    const int rsl = (g16 ^ ((fr >> 1) & 3)) * 8;      // swizzled elem col
    const int rA  = wrm * 64 + fr;                    // + m*16
    const int rB  = wcn * 64 + fr;                    // + n*16

    f32x4 acc[4][4];
#pragma unroll
    for (int m = 0; m < 4; ++m)
#pragma unroll
        for (int n = 0; n < 4; ++n)
            acc[m][n] = (f32x4){0.f, 0.f, 0.f, 0.f};

    f32x4 regA[4];
    auto gloadA = [&](int t) {
#pragma unroll
        for (int j = 0; j < 4; ++j)
            regA[j] = *(const f32x4*)(Asrc + t * 32 + j * 4);
    };
    auto cwA = [&](bf16* abase) {
        bf16x8 w0, w1;
#pragma unroll
        for (int j = 0; j < 4; ++j) {
            w0[j]     = (bf16)regA[0][j];
            w0[j + 4] = (bf16)regA[1][j];
            w1[j]     = (bf16)regA[2][j];
            w1[j + 4] = (bf16)regA[3][j];
        }
        *(bf16x8*)&abase[woff0] = w0;
        *(bf16x8*)&abase[woff1] = w1;
    };
    // B: 2 x global_load_lds per wave. PER-LANE global src (+lane*8 elems);
    // wave-uniform LDS dest (HW adds lane*16 bytes).
    auto stageB = [&](int t, bf16* bbase) {
#pragma unroll
        for (int q = 0; q < 2; ++q) {
            const bf16* s = Bip + (size_t)t * 4096 + (wid * 2 + q) * 512 + lane * 8;
            __builtin_amdgcn_global_load_lds(
                (const __attribute__((address_space(1))) void*)s,
                (__attribute__((address_space(3))) void*)(bbase + (wid * 2 + q) * 512),
                16, 0, 0);
        }
    };

    // ---- prologue ----
    stageB(0, lds + 8192);            // B[0]
    gloadA(0);
    asm volatile("s_waitcnt vmcnt(0)" ::: "memory");
    cwA(lds);                         // A[0]
    gloadA(1);
    asm volatile("s_waitcnt lgkmcnt(0)" ::: "memory");
    __builtin_amdgcn_s_barrier();

    for (int t = 0; t < NT; ++t) {
        const int p = t & 1;
        bf16* Ab  = lds + p * 4096;
        bf16* Bb  = lds + 8192 + p * 4096;
        bf16* Abn = lds + (p ^ 1) * 4096;
        bf16* Bbn = lds + 8192 + (p ^ 1) * 4096;

        if (t + 1 < NT) {
            stageB(t + 1, Bbn);                                   // s0
            asm volatile("s_waitcnt vmcnt(2)" ::: "memory");      // s1: A(t+1) regs ready
            cwA(Abn);
            if (t + 2 < NT) gloadA(t + 2);                        // s2
        }

        bf16x8 af[4], bv[4];                                      // s3
#pragma unroll
        for (int m = 0; m < 4; ++m)
            af[m] = *(const bf16x8*)&Ab[(rA + m * 16) * 32 + rsl];
#pragma unroll
        for (int n = 0; n < 4; ++n)
            bv[n] = *(const bf16x8*)&Bb[(rB + n * 16) * 32 + rsl];

        if (t + 2 < NT)      asm volatile("s_waitcnt vmcnt(4)" ::: "memory");  // s4
        else if (t + 1 < NT) asm volatile("s_waitcnt vmcnt(0)" ::: "memory");
        asm volatile("s_waitcnt lgkmcnt(0)" ::: "memory");        // s5
        __builtin_amdgcn_s_barrier();

        __builtin_amdgcn_s_setprio(1);                            // s6
#pragma unroll
        for (int n = 0; n < 4; ++n)
#pragma unroll
            for (int m = 0; m < 4; ++m)
                acc[m][n] = __builtin_amdgcn_mfma_f32_16x16x32_bf16(af[m], bv[n], acc[m][n], 0, 0, 0);
        __builtin_amdgcn_s_setprio(0);
    }

    // ---- epilogue: bias (+ exp for logvar head) ----
    const bool is_mu = (bn < 4);
    const float* __restrict__ bias = is_mu ? b_mu : b_logvar;
    const int cb = (bn & 3) * 128;
    float* __restrict__ obase = is_mu ? out : (out + (size_t)M_TOT * D_EMB);

#pragma unroll
    for (int m = 0; m < 4; ++m) {
        const int row0 = bm * 128 + wrm * 64 + m * 16 + g16 * 4;
#pragma unroll
        for (int n = 0; n < 4; ++n) {
            const int c = cb + wcn * 64 + n * 16 + fr;
            const float bvs = bias[c];
#pragma unroll
            for (int j = 0; j < 4; ++j) {
                float v = acc[m][n][j] + bvs;
                if (!is_mu) v = __expf(0.5f * v);
                obase[(size_t)(row0 + j) * D_EMB + c] = v;
            }
        }
    }
}

// ============================================================
// Fallback (no workspace): round-1 f32-staging GEMM
// ============================================================
#define LDS_STRIDE 40
__global__ __launch_bounds__(256) void gpe_gemm_fb(
    const float* __restrict__ x, const float* __restrict__ W_mu,
    const float* __restrict__ b_mu, const float* __restrict__ W_logvar,
    const float* __restrict__ b_logvar, float* __restrict__ out)
{
    __shared__ __align__(16) bf16 As[128][LDS_STRIDE];
    __shared__ __align__(16) bf16 Bs[128][LDS_STRIDE];
    typedef __attribute__((ext_vector_type(4))) bf16 bf16x4;
    const int tid = threadIdx.x, lane = tid & 63, wid = tid >> 6;
    const int wr = wid >> 1, wc = wid & 1;
    const int bn = blockIdx.x & 7, bm = blockIdx.x >> 3;
    const int ebase = bn * 128;
    const bool is_mu = (ebase < D_EMB);
    const float* Wp = is_mu ? (W_mu + (size_t)ebase * K_TOT)
                            : (W_logvar + (size_t)(ebase - D_EMB) * K_TOT);
    const float* bias = is_mu ? b_mu : b_logvar;
    const int cbase = is_mu ? ebase : (ebase - D_EMB);
    float* obase = is_mu ? out : (out + (size_t)M_TOT * D_EMB);
    const float* Ap = x + (size_t)(bm * 128) * K_TOT;
    f32x4 acc[4][4];
#pragma unroll
    for (int m = 0; m < 4; ++m)
#pragma unroll
        for (int n = 0; n < 4; ++n) acc[m][n] = (f32x4){0.f, 0.f, 0.f, 0.f};
    const int fr = lane & 15, fk = (lane >> 4) * 8;
    const int arow = wr * 64 + fr, brow = wc * 64 + fr;
    for (int kt = 0; kt < K_TOT / 32; ++kt) {
        const int k0 = kt * 32;
#pragma unroll
        for (int s = 0; s < 4; ++s) {
            const int idx = s * 256 + tid;
            const int row = idx >> 3, col = (idx & 7) << 2;
            f32x4 va = *reinterpret_cast<const f32x4*>(Ap + (size_t)row * K_TOT + k0 + col);
            f32x4 vb = *reinterpret_cast<const f32x4*>(Wp + (size_t)row * K_TOT + k0 + col);
            bf16x4 ha, hb;
#pragma unroll
            for (int j = 0; j < 4; ++j) { ha[j] = (bf16)va[j]; hb[j] = (bf16)vb[j]; }
            *reinterpret_cast<bf16x4*>(&As[row][col]) = ha;
            *reinterpret_cast<bf16x4*>(&Bs[row][col]) = hb;
        }
        __syncthreads();
        bf16x8 af[4], bfv[4];
#pragma unroll
        for (int m = 0; m < 4; ++m)
            af[m] = *reinterpret_cast<const bf16x8*>(&As[arow + m * 16][fk]);
#pragma unroll
        for (int n = 0; n < 4; ++n)
            bfv[n] = *reinterpret_cast<const bf16x8*>(&Bs[brow + n * 16][fk]);
#pragma unroll
        for (int m = 0; m < 4; ++m)
#pragma unroll
            for (int n = 0; n < 4; ++n)
                acc[m][n] = __builtin_amdgcn_mfma_f32_16x16x32_bf16(af[m], bfv[n], acc[m][n], 0, 0, 0);
        __syncthreads();
    }
#pragma unroll
    for (int m = 0; m < 4; ++m) {
        const int rbase = bm * 128 + wr * 64 + m * 16 + (lane >> 4) * 4;
#pragma unroll
        for (int n = 0; n < 4; ++n) {
            const int c = cbase + wc * 64 + n * 16 + (lane & 15);
            const float bv = bias[c];
#pragma unroll
            for (int j = 0; j < 4; ++j) {
                float v = acc[m][n][j] + bv;
                if (!is_mu) v = __expf(0.5f * v);
                obase[(size_t)(rbase + j) * D_EMB + c] = v;
            }
        }
    }
}

extern "C" void kernel_launch(void* const* d_in, const int* in_sizes, int n_in,
                              void* d_out, int out_size, void* d_ws, size_t ws_size,
                              hipStream_t stream) {
    const float* x        = (const float*)d_in[0];
    const float* W_mu     = (const float*)d_in[1];
    const float* b_mu     = (const float*)d_in[2];
    const float* W_logvar = (const float*)d_in[3];
    const float* b_logvar = (const float*)d_in[4];
    float* out = (float*)d_out;

    const size_t ws_needed = (size_t)1024 * 1024 * sizeof(bf16);   // 2 MB W image

    if (ws_size >= ws_needed) {
        bf16* wimg = (bf16*)d_ws;
        cvt_w_img<<<512, 256, 0, stream>>>(W_mu, W_logvar, wimg);
        gpe_gemm<<<1024, 256, 0, stream>>>(x, wimg, b_mu, b_logvar, out);
    } else {
        gpe_gemm_fb<<<1024, 256, 0, stream>>>(x, W_mu, b_mu, W_logvar, b_logvar, out);
    }
}

// Round 9
// 51.117 us; speedup vs baseline: 1.2821x; 1.2821x over previous
//
#include <hip/hip_runtime.h>
#include <hip/hip_bf16.h>
#include <math.h>

typedef __bf16 bf16;
typedef __attribute__((ext_vector_type(4))) float f32x4;
typedef __attribute__((ext_vector_type(8))) bf16 bf16x8;

#define M_TOT 16384
#define K_TOT 1024
#define D_EMB 512
#define NT 32          // K tiles of 32

// ============================================================
// Pass 0: W (both heads) -> fragment-ordered bf16 image (2 MB).
// Blob (estrip, kt) = 1 KB: img[((estrip*32 + kt)*64 + lane)*8 + j]
//   = W_cat[estrip*16 + (lane&15)][kt*32 + (lane>>4)*8 + j]
// i.e. exactly one wave's 16x16x32 B-fragment as a contiguous,
// lane-major 1 KB block -> GEMM loads B global->VGPR coalesced,
// no LDS, no swizzle, register reuse across m.
// ============================================================
__global__ __launch_bounds__(256) void cvt_w_img(
    const float* __restrict__ W_mu, const float* __restrict__ W_logvar,
    bf16* __restrict__ img)
{
    const int c  = blockIdx.x * 256 + threadIdx.x;   // 0..131071
    const int l  = c & 63;
    const int kt = (c >> 6) & 31;
    const int es = c >> 11;                          // 0..63
    const int col = es * 16 + (l & 15);
    const int k0  = kt * 32 + (l >> 4) * 8;
    const float* s = (col < D_EMB) ? (W_mu + (size_t)col * K_TOT + k0)
                                   : (W_logvar + (size_t)(col - D_EMB) * K_TOT + k0);
    f32x4 a = ((const f32x4*)s)[0];
    f32x4 b = ((const f32x4*)s)[1];
    bf16x8 o;
    o[0] = (bf16)a[0]; o[1] = (bf16)a[1]; o[2] = (bf16)a[2]; o[3] = (bf16)a[3];
    o[4] = (bf16)b[0]; o[5] = (bf16)b[1]; o[6] = (bf16)b[2]; o[7] = (bf16)b[3];
    *(bf16x8*)(img + (size_t)c * 8) = o;
}

// ============================================================
// Main GEMM: 256x256 tile, BK=32, 8 waves (2m x 4n), wave-tile
// 128x64. A: x f32 -> regs -> cvt -> swizzled ds_write (measured
// conflict-free geometry from r6), double-buffered 32 KB LDS.
// B: direct global->VGPR from the W image (L2-resident, 4 KB/wave
// /tile), ping-pong register sets, NO LDS, NO barrier interaction.
// One barrier per K-tile.
// Ledger (FIFO per wave; invariant entering tile t: [B(t):4, A(t+1):4]):
//   1. vmcnt(4)            -> B(t) frags resident
//   2. issue gloadB(t+1)   -> [A(t+1):4, B(t+1):4]
//   3. vmcnt(4)            -> A(t+1) f32 regs resident
//   4. cvt + ds_write A(t+1) -> buf p^1
//   5. issue gloadA(t+2)   -> [B(t+1):4, A(t+2):4]  (= invariant t+1)
//   6. ds_read af[8] from buf p
//   7. lgkm(0); barrier    (write visibility + af ready)
//   8. setprio(1); 32 MFMA (af x bv(t)); setprio(0)
// Tails guarded by t+1/t+2 < NT; last tile drains vmcnt(0). WAR on
// buf p^1: its readers ran at tile t-1 and drained lgkm before
// barrier(t-1), which precedes these writes.
// ============================================================
__global__ __launch_bounds__(512, 2) void gpe_gemm(
    const float* __restrict__ x,
    const bf16* __restrict__ wimg,
    const float* __restrict__ b_mu,
    const float* __restrict__ b_logvar,
    float* __restrict__ out)         // [2][16384][512]
{
    __shared__ __align__(16) bf16 Alds[2 * 256 * 32];   // 32 KB

    const int tid  = threadIdx.x;
    const int lane = tid & 63;
    const int wid  = tid >> 6;        // 0..7
    const int wr   = wid >> 2;        // 0..1  (m half)
    const int wc   = wid & 3;         // 0..3  (n quarter)

    // T1: bijective XCD swizzle (grid 256 = 8 XCD x 32); bn inner.
    const int bid = blockIdx.x;
    const int swz = (bid & 7) * 32 + (bid >> 3);
    const int bn  = swz & 3;          // 0..3 (E quadrant)
    const int bm  = swz >> 2;         // 0..63

    // ---- A staging geometry: thread owns 16 f32 of one row ----
    const int r_l  = tid >> 1;                        // 0..255
    const int half = tid & 1;
    const float* __restrict__ Asrc = x + (size_t)(bm * 256 + r_l) * K_TOT + half * 16;
    const int wxor  = (r_l >> 1) & 3;
    const int woff0 = r_l * 32 + ((half * 2 + 0) ^ wxor) * 8;   // elems
    const int woff1 = r_l * 32 + ((half * 2 + 1) ^ wxor) * 8;

    // ---- frag geometry ----
    const int fr  = lane & 15;
    const int g16 = lane >> 4;
    const int rsl = (g16 ^ ((fr >> 1) & 3)) * 8;      // swizzled elem col
    const int rA  = wr * 128 + fr;                    // + m*16, m=0..7

    // ---- B image base: 4 estrips per wave ----
    const bf16* __restrict__ bb =
        wimg + (size_t)(bn * 16 + wc * 4) * 16384 + lane * 8;
    // frag (n, kt) at: bb + n*16384 + kt*512

    f32x4 acc[8][4];
#pragma unroll
    for (int m = 0; m < 8; ++m)
#pragma unroll
        for (int n = 0; n < 4; ++n)
            acc[m][n] = (f32x4){0.f, 0.f, 0.f, 0.f};

    f32x4 regA[4];
    auto gloadA = [&](int t) {
#pragma unroll
        for (int j = 0; j < 4; ++j)
            regA[j] = *(const f32x4*)(Asrc + t * 32 + j * 4);
    };
    auto cwA = [&](bf16* abase) {
        bf16x8 w0, w1;
#pragma unroll
        for (int j = 0; j < 4; ++j) {
            w0[j]     = (bf16)regA[0][j];
            w0[j + 4] = (bf16)regA[1][j];
            w1[j]     = (bf16)regA[2][j];
            w1[j + 4] = (bf16)regA[3][j];
        }
        *(bf16x8*)&abase[woff0] = w0;
        *(bf16x8*)&abase[woff1] = w1;
    };
    auto gloadB = [&](int t, bf16x8 (&bv)[4]) {
#pragma unroll
        for (int n = 0; n < 4; ++n)
            bv[n] = *(const bf16x8*)(bb + (size_t)n * 16384 + t * 512);
    };

    bf16x8 bvA[4], bvB[4];

    // ---- prologue ----
    gloadA(0);
    asm volatile("s_waitcnt vmcnt(0)" ::: "memory");
    cwA(Alds);                        // buf 0
    gloadB(0, bvA);
    gloadA(1);
    asm volatile("s_waitcnt lgkmcnt(0)" ::: "memory");
    __builtin_amdgcn_s_barrier();
    // outstanding: [B0:4, A1:4]

#define TILE_BODY(T, P, BVC, BVN)                                              \
    {                                                                          \
        const int t = (T);                                                     \
        bf16* Ab  = Alds + (P) * 8192;                                         \
        bf16* Abn = Alds + ((P) ^ 1) * 8192;                                   \
        if (t + 1 < NT) asm volatile("s_waitcnt vmcnt(4)" ::: "memory");       \
        else            asm volatile("s_waitcnt vmcnt(0)" ::: "memory");       \
        if (t + 1 < NT) {                                                      \
            gloadB(t + 1, BVN);                                                \
            asm volatile("s_waitcnt vmcnt(4)" ::: "memory");                   \
            cwA(Abn);                                                          \
            if (t + 2 < NT) gloadA(t + 2);                                     \
        }                                                                      \
        bf16x8 af[8];                                                          \
        _Pragma("unroll")                                                      \
        for (int m = 0; m < 8; ++m)                                            \
            af[m] = *(const bf16x8*)&Ab[(rA + m * 16) * 32 + rsl];             \
        asm volatile("s_waitcnt lgkmcnt(0)" ::: "memory");                     \
        __builtin_amdgcn_s_barrier();                                          \
        __builtin_amdgcn_s_setprio(1);                                         \
        _Pragma("unroll")                                                      \
        for (int n = 0; n < 4; ++n)                                            \
            _Pragma("unroll")                                                  \
            for (int m = 0; m < 8; ++m)                                        \
                acc[m][n] = __builtin_amdgcn_mfma_f32_16x16x32_bf16(           \
                    af[m], BVC[n], acc[m][n], 0, 0, 0);                        \
        __builtin_amdgcn_s_setprio(0);                                         \
    }

    for (int tt = 0; tt < NT; tt += 2) {
        TILE_BODY(tt,     0, bvA, bvB)
        TILE_BODY(tt + 1, 1, bvB, bvA)
    }
#undef TILE_BODY

    // ---- epilogue: bias (+ exp for logvar head) ----
    const bool is_mu = (bn < 2);
    const float* __restrict__ bias = is_mu ? b_mu : b_logvar;
    const int cb = (bn & 1) * 256;
    float* __restrict__ obase = is_mu ? out : (out + (size_t)M_TOT * D_EMB);

#pragma unroll
    for (int m = 0; m < 8; ++m) {
        const int row0 = bm * 256 + wr * 128 + m * 16 + g16 * 4;
#pragma unroll
        for (int n = 0; n < 4; ++n) {
            const int c = cb + wc * 64 + n * 16 + fr;
            const float bvs = bias[c];
#pragma unroll
            for (int j = 0; j < 4; ++j) {
                float v = acc[m][n][j] + bvs;
                if (!is_mu) v = __expf(0.5f * v);
                obase[(size_t)(row0 + j) * D_EMB + c] = v;
            }
        }
    }
}

// ============================================================
// Fallback (no workspace): round-1 f32-staging GEMM
// ============================================================
#define LDS_STRIDE 40
__global__ __launch_bounds__(256) void gpe_gemm_fb(
    const float* __restrict__ x, const float* __restrict__ W_mu,
    const float* __restrict__ b_mu, const float* __restrict__ W_logvar,
    const float* __restrict__ b_logvar, float* __restrict__ out)
{
    __shared__ __align__(16) bf16 As[128][LDS_STRIDE];
    __shared__ __align__(16) bf16 Bs[128][LDS_STRIDE];
    typedef __attribute__((ext_vector_type(4))) bf16 bf16x4;
    const int tid = threadIdx.x, lane = tid & 63, wid = tid >> 6;
    const int wr = wid >> 1, wc = wid & 1;
    const int bn = blockIdx.x & 7, bm = blockIdx.x >> 3;
    const int ebase = bn * 128;
    const bool is_mu = (ebase < D_EMB);
    const float* Wp = is_mu ? (W_mu + (size_t)ebase * K_TOT)
                            : (W_logvar + (size_t)(ebase - D_EMB) * K_TOT);
    const float* bias = is_mu ? b_mu : b_logvar;
    const int cbase = is_mu ? ebase : (ebase - D_EMB);
    float* obase = is_mu ? out : (out + (size_t)M_TOT * D_EMB);
    const float* Ap = x + (size_t)(bm * 128) * K_TOT;
    f32x4 acc[4][4];
#pragma unroll
    for (int m = 0; m < 4; ++m)
#pragma unroll
        for (int n = 0; n < 4; ++n) acc[m][n] = (f32x4){0.f, 0.f, 0.f, 0.f};
    const int fr = lane & 15, fk = (lane >> 4) * 8;
    const int arow = wr * 64 + fr, brow = wc * 64 + fr;
    for (int kt = 0; kt < K_TOT / 32; ++kt) {
        const int k0 = kt * 32;
#pragma unroll
        for (int s = 0; s < 4; ++s) {
            const int idx = s * 256 + tid;
            const int row = idx >> 3, col = (idx & 7) << 2;
            f32x4 va = *reinterpret_cast<const f32x4*>(Ap + (size_t)row * K_TOT + k0 + col);
            f32x4 vb = *reinterpret_cast<const f32x4*>(Wp + (size_t)row * K_TOT + k0 + col);
            bf16x4 ha, hb;
#pragma unroll
            for (int j = 0; j < 4; ++j) { ha[j] = (bf16)va[j]; hb[j] = (bf16)vb[j]; }
            *reinterpret_cast<bf16x4*>(&As[row][col]) = ha;
            *reinterpret_cast<bf16x4*>(&Bs[row][col]) = hb;
        }
        __syncthreads();
        bf16x8 af[4], bfv[4];
#pragma unroll
        for (int m = 0; m < 4; ++m)
            af[m] = *reinterpret_cast<const bf16x8*>(&As[arow + m * 16][fk]);
#pragma unroll
        for (int n = 0; n < 4; ++n)
            bfv[n] = *reinterpret_cast<const bf16x8*>(&Bs[brow + n * 16][fk]);
#pragma unroll
        for (int m = 0; m < 4; ++m)
#pragma unroll
            for (int n = 0; n < 4; ++n)
                acc[m][n] = __builtin_amdgcn_mfma_f32_16x16x32_bf16(af[m], bfv[n], acc[m][n], 0, 0, 0);
        __syncthreads();
    }
#pragma unroll
    for (int m = 0; m < 4; ++m) {
        const int rbase = bm * 128 + wr * 64 + m * 16 + (lane >> 4) * 4;
#pragma unroll
        for (int n = 0; n < 4; ++n) {
            const int c = cbase + wc * 64 + n * 16 + (lane & 15);
            const float bv = bias[c];
#pragma unroll
            for (int j = 0; j < 4; ++j) {
                float v = acc[m][n][j] + bv;
                if (!is_mu) v = __expf(0.5f * v);
                obase[(size_t)(rbase + j) * D_EMB + c] = v;
            }
        }
    }
}

extern "C" void kernel_launch(void* const* d_in, const int* in_sizes, int n_in,
                              void* d_out, int out_size, void* d_ws, size_t ws_size,
                              hipStream_t stream) {
    const float* x        = (const float*)d_in[0];
    const float* W_mu     = (const float*)d_in[1];
    const float* b_mu     = (const float*)d_in[2];
    const float* W_logvar = (const float*)d_in[3];
    const float* b_logvar = (const float*)d_in[4];
    float* out = (float*)d_out;

    const size_t ws_needed = (size_t)1024 * 1024 * sizeof(bf16);   // 2 MB W image

    if (ws_size >= ws_needed) {
        bf16* wimg = (bf16*)d_ws;
        cvt_w_img<<<512, 256, 0, stream>>>(W_mu, W_logvar, wimg);
        gpe_gemm<<<256, 512, 0, stream>>>(x, wimg, b_mu, b_logvar, out);
    } else {
        gpe_gemm_fb<<<1024, 256, 0, stream>>>(x, W_mu, b_mu, W_logvar, b_logvar, out);
    }
}